// Round 1
// baseline (844.249 us; speedup 1.0000x reference)
//
#include <hip/hip_runtime.h>

#define D 64

// ---------------------------------------------------------------------------
// Scatter-sum: one wave (64 lanes) per edge. Lane d handles feature dim d.
// feat row read is coalesced (256B per wave); atomicAdd into agg[dst].
// cnt != nullptr -> also accumulate in-degree (layer 1 only).
// ---------------------------------------------------------------------------
__global__ void scatter_sum_kernel(const float* __restrict__ feat,
                                   const int* __restrict__ src,
                                   const int* __restrict__ dst,
                                   float* __restrict__ agg,
                                   float* __restrict__ cnt,
                                   int n_edges) {
    int lane   = threadIdx.x & 63;
    int wave   = (int)((blockIdx.x * blockDim.x + threadIdx.x) >> 6);
    int nwaves = (int)((gridDim.x * blockDim.x) >> 6);
    for (int e = wave; e < n_edges; e += nwaves) {
        int s  = src[e];
        int d0 = dst[e];
        float v = feat[(size_t)s * D + lane];
        atomicAdd(&agg[(size_t)d0 * D + lane], v);
        if (cnt != nullptr && lane == 0) atomicAdd(&cnt[d0], 1.0f);
    }
}

// ---------------------------------------------------------------------------
// Fused SAGE linear: out = [relu]( (agg/max(cnt,1)) @ Wl + xin @ Wr + b )
// One wave per node; lane j computes output feature j. W matrices staged in
// LDS; node row values broadcast across the wave via __shfl.
// out may alias agg (each wave reads its full agg row before writing out row).
// ---------------------------------------------------------------------------
__global__ void sage_linear_kernel(const float* __restrict__ agg,
                                   const float* __restrict__ cnt,
                                   const float* __restrict__ xin,
                                   const float* __restrict__ Wl,
                                   const float* __restrict__ Wr,
                                   const float* __restrict__ bias,
                                   float* __restrict__ out,
                                   int n_nodes, int do_relu) {
    __shared__ float sWl[D * D];
    __shared__ float sWr[D * D];
    for (int i = threadIdx.x; i < D * D; i += blockDim.x) {
        sWl[i] = Wl[i];
        sWr[i] = Wr[i];
    }
    __syncthreads();

    int lane   = threadIdx.x & 63;
    int wib    = threadIdx.x >> 6;
    int wpb    = blockDim.x >> 6;
    int wave   = blockIdx.x * wpb + wib;
    int nwaves = gridDim.x * wpb;
    float bj = bias[lane];

    for (int node = wave; node < n_nodes; node += nwaves) {
        float c   = cnt[node];
        float inv = 1.0f / fmaxf(c, 1.0f);
        float m   = agg[(size_t)node * D + lane] * inv;   // mean row elem
        float xv  = xin[(size_t)node * D + lane];         // x row elem
        float acc = bj;
#pragma unroll
        for (int k = 0; k < D; ++k) {
            acc += __shfl(m, k)  * sWl[k * D + lane];
            acc += __shfl(xv, k) * sWr[k * D + lane];
        }
        if (do_relu) acc = fmaxf(acc, 0.0f);
        out[(size_t)node * D + lane] = acc;
    }
}

// ---------------------------------------------------------------------------
// Edge decode: out[e] = dot(z[src_e], z[dst_e]). One wave per edge,
// 64-lane shuffle reduction.
// ---------------------------------------------------------------------------
__global__ void decode_kernel(const float* __restrict__ z,
                              const int* __restrict__ esrc,
                              const int* __restrict__ edst,
                              float* __restrict__ out,
                              int n) {
    int lane   = threadIdx.x & 63;
    int wave   = (int)((blockIdx.x * blockDim.x + threadIdx.x) >> 6);
    int nwaves = (int)((gridDim.x * blockDim.x) >> 6);
    for (int e = wave; e < n; e += nwaves) {
        int s  = esrc[e];
        int d0 = edst[e];
        float p = z[(size_t)s * D + lane] * z[(size_t)d0 * D + lane];
#pragma unroll
        for (int off = 32; off > 0; off >>= 1) p += __shfl_down(p, off);
        if (lane == 0) out[e] = p;
    }
}

extern "C" void kernel_launch(void* const* d_in, const int* in_sizes, int n_in,
                              void* d_out, int out_size, void* d_ws, size_t ws_size,
                              hipStream_t stream) {
    const float* x   = (const float*)d_in[0];
    const int*   ei  = (const int*)d_in[1];   // [2, E] row-major: src row then dst row
    const int*   eli = (const int*)d_in[2];   // [2, L]
    const float* W1l = (const float*)d_in[3];
    const float* W1r = (const float*)d_in[4];
    const float* b1  = (const float*)d_in[5];
    const float* W2l = (const float*)d_in[6];
    const float* W2r = (const float*)d_in[7];
    const float* b2  = (const float*)d_in[8];
    float* out = (float*)d_out;

    const int n_nodes = in_sizes[0] / D;
    const int n_edges = in_sizes[1] / 2;
    const int n_label = in_sizes[2] / 2;

    const int* e_src = ei;
    const int* e_dst = ei + n_edges;
    const int* l_src = eli;
    const int* l_dst = eli + n_label;

    // Workspace layout (floats):
    //   bufA: N*D  (agg layer1 -> agg layer2 -> z in-place)
    //   cnt : N
    //   h   : N*D
    float* bufA = (float*)d_ws;
    float* cnt  = bufA + (size_t)n_nodes * D;
    float* h    = cnt + n_nodes;

    const size_t feat_bytes = (size_t)n_nodes * D * sizeof(float);

    dim3 blk(256);
    dim3 grd_scatter(4096);
    dim3 grd_linear(2048);
    dim3 grd_decode(2048);

    // ---- Layer 1 ----
    hipMemsetAsync(bufA, 0, feat_bytes, stream);
    hipMemsetAsync(cnt, 0, (size_t)n_nodes * sizeof(float), stream);
    scatter_sum_kernel<<<grd_scatter, blk, 0, stream>>>(x, e_src, e_dst, bufA, cnt, n_edges);
    sage_linear_kernel<<<grd_linear, blk, 0, stream>>>(bufA, cnt, x, W1l, W1r, b1, h,
                                                       n_nodes, /*relu=*/1);

    // ---- Layer 2 ----
    hipMemsetAsync(bufA, 0, feat_bytes, stream);
    scatter_sum_kernel<<<grd_scatter, blk, 0, stream>>>(h, e_src, e_dst, bufA, nullptr, n_edges);
    // z written in-place over bufA (each wave reads its agg row before writing)
    sage_linear_kernel<<<grd_linear, blk, 0, stream>>>(bufA, cnt, h, W2l, W2r, b2, bufA,
                                                       n_nodes, /*relu=*/0);

    // ---- Decode ----
    decode_kernel<<<grd_decode, blk, 0, stream>>>(bufA, l_src, l_dst, out, n_label);
}

// Round 2
// 555.866 us; speedup vs baseline: 1.5188x; 1.5188x over previous
//
#include <hip/hip_runtime.h>

#define D 64
#define SCAN_BLK 1024

// ---------------------------------------------------------------------------
// CSR build step 1: degree histogram (int atomics on cache-resident bins)
// ---------------------------------------------------------------------------
__global__ void hist_kernel(const int* __restrict__ dst, int* __restrict__ deg,
                            int n_edges) {
    int i = blockIdx.x * blockDim.x + threadIdx.x;
    int stride = gridDim.x * blockDim.x;
    for (int e = i; e < n_edges; e += stride) atomicAdd(&deg[dst[e]], 1);
}

// ---------------------------------------------------------------------------
// 3-kernel exclusive scan over deg[n] -> row_ptr[n] (+ row_ptr[n] = n_edges)
// ---------------------------------------------------------------------------
__global__ void scan1_kernel(const int* __restrict__ in, int* __restrict__ out,
                             int* __restrict__ bsum, int n) {
    __shared__ int tmp[SCAN_BLK];
    int gid = blockIdx.x * SCAN_BLK + threadIdx.x;
    int v = (gid < n) ? in[gid] : 0;
    tmp[threadIdx.x] = v;
    __syncthreads();
    for (int off = 1; off < SCAN_BLK; off <<= 1) {
        int t = 0;
        if ((int)threadIdx.x >= off) t = tmp[threadIdx.x - off];
        __syncthreads();
        if ((int)threadIdx.x >= off) tmp[threadIdx.x] += t;
        __syncthreads();
    }
    if (gid < n) out[gid] = tmp[threadIdx.x] - v;  // exclusive
    if (threadIdx.x == SCAN_BLK - 1) bsum[blockIdx.x] = tmp[SCAN_BLK - 1];
}

__global__ void scan2_kernel(int* __restrict__ bsum, int nb) {
    __shared__ int tmp[128];
    int tid = threadIdx.x;
    int v = (tid < nb) ? bsum[tid] : 0;
    tmp[tid] = v;
    __syncthreads();
    for (int off = 1; off < 128; off <<= 1) {
        int t = 0;
        if (tid >= off) t = tmp[tid - off];
        __syncthreads();
        if (tid >= off) tmp[tid] += t;
        __syncthreads();
    }
    if (tid < nb) bsum[tid] = tmp[tid] - v;  // exclusive block offsets
}

__global__ void scan3_kernel(int* __restrict__ out, const int* __restrict__ bsum,
                             int n, int total) {
    int gid = blockIdx.x * SCAN_BLK + threadIdx.x;
    if (gid < n) out[gid] += bsum[blockIdx.x];
    if (gid == 0) out[n] = total;
}

// ---------------------------------------------------------------------------
// CSR build step 3: place each edge's src id into its dst segment.
// Order within a segment is arbitrary (sum is order-insensitive to tolerance).
// ---------------------------------------------------------------------------
__global__ void scatter_ids_kernel(const int* __restrict__ src,
                                   const int* __restrict__ dst,
                                   int* __restrict__ cursor,
                                   int* __restrict__ sorted_src,
                                   int n_edges) {
    int i = blockIdx.x * blockDim.x + threadIdx.x;
    int stride = gridDim.x * blockDim.x;
    for (int e = i; e < n_edges; e += stride) {
        int pos = atomicAdd(&cursor[dst[e]], 1);
        sorted_src[pos] = src[e];
    }
}

// ---------------------------------------------------------------------------
// Mean aggregation: one wave per node, lane d owns feature dim d.
// No atomics; each output row written exactly once (as the mean).
// ---------------------------------------------------------------------------
__global__ void aggregate_kernel(const float* __restrict__ feat,
                                 const int* __restrict__ row_ptr,
                                 const int* __restrict__ sorted_src,
                                 float* __restrict__ mean_out,
                                 int n_nodes) {
    int lane   = threadIdx.x & 63;
    int wave   = (int)((blockIdx.x * blockDim.x + threadIdx.x) >> 6);
    int nwaves = (int)((gridDim.x * blockDim.x) >> 6);
    for (int node = wave; node < n_nodes; node += nwaves) {
        int beg = row_ptr[node];
        int end = row_ptr[node + 1];
        float acc = 0.0f;
        int i = beg;
        for (; i + 4 <= end; i += 4) {  // 4-wide MLP for latency hiding
            int s0 = sorted_src[i], s1 = sorted_src[i + 1];
            int s2 = sorted_src[i + 2], s3 = sorted_src[i + 3];
            float v0 = feat[(size_t)s0 * D + lane];
            float v1 = feat[(size_t)s1 * D + lane];
            float v2 = feat[(size_t)s2 * D + lane];
            float v3 = feat[(size_t)s3 * D + lane];
            acc += (v0 + v1) + (v2 + v3);
        }
        for (; i < end; ++i) acc += feat[(size_t)sorted_src[i] * D + lane];
        float inv = 1.0f / (float)max(end - beg, 1);
        mean_out[(size_t)node * D + lane] = acc * inv;
    }
}

// ---------------------------------------------------------------------------
// Fused SAGE linear: out = [relu]( mean @ Wl + xin @ Wr + b )
// One wave per node; lane j computes output feature j.
// out may alias mean (full row read before row write).
// ---------------------------------------------------------------------------
__global__ void sage_linear_kernel(const float* __restrict__ mean,
                                   const float* __restrict__ xin,
                                   const float* __restrict__ Wl,
                                   const float* __restrict__ Wr,
                                   const float* __restrict__ bias,
                                   float* __restrict__ out,
                                   int n_nodes, int do_relu) {
    __shared__ float sWl[D * D];
    __shared__ float sWr[D * D];
    for (int i = threadIdx.x; i < D * D; i += blockDim.x) {
        sWl[i] = Wl[i];
        sWr[i] = Wr[i];
    }
    __syncthreads();

    int lane   = threadIdx.x & 63;
    int wib    = threadIdx.x >> 6;
    int wpb    = blockDim.x >> 6;
    int wave   = blockIdx.x * wpb + wib;
    int nwaves = gridDim.x * wpb;
    float bj = bias[lane];

    for (int node = wave; node < n_nodes; node += nwaves) {
        float m  = mean[(size_t)node * D + lane];
        float xv = xin[(size_t)node * D + lane];
        float acc = bj;
#pragma unroll
        for (int k = 0; k < D; ++k) {
            acc += __shfl(m, k)  * sWl[k * D + lane];
            acc += __shfl(xv, k) * sWr[k * D + lane];
        }
        if (do_relu) acc = fmaxf(acc, 0.0f);
        out[(size_t)node * D + lane] = acc;
    }
}

// ---------------------------------------------------------------------------
// Edge decode: out[e] = dot(z[src_e], z[dst_e]).
// ---------------------------------------------------------------------------
__global__ void decode_kernel(const float* __restrict__ z,
                              const int* __restrict__ esrc,
                              const int* __restrict__ edst,
                              float* __restrict__ out,
                              int n) {
    int lane   = threadIdx.x & 63;
    int wave   = (int)((blockIdx.x * blockDim.x + threadIdx.x) >> 6);
    int nwaves = (int)((gridDim.x * blockDim.x) >> 6);
    for (int e = wave; e < n; e += nwaves) {
        int s  = esrc[e];
        int d0 = edst[e];
        float p = z[(size_t)s * D + lane] * z[(size_t)d0 * D + lane];
#pragma unroll
        for (int off = 32; off > 0; off >>= 1) p += __shfl_down(p, off);
        if (lane == 0) out[e] = p;
    }
}

extern "C" void kernel_launch(void* const* d_in, const int* in_sizes, int n_in,
                              void* d_out, int out_size, void* d_ws, size_t ws_size,
                              hipStream_t stream) {
    const float* x   = (const float*)d_in[0];
    const int*   ei  = (const int*)d_in[1];   // [2, E]: src row then dst row
    const int*   eli = (const int*)d_in[2];   // [2, L]
    const float* W1l = (const float*)d_in[3];
    const float* W1r = (const float*)d_in[4];
    const float* b1  = (const float*)d_in[5];
    const float* W2l = (const float*)d_in[6];
    const float* W2r = (const float*)d_in[7];
    const float* b2  = (const float*)d_in[8];
    float* out = (float*)d_out;

    const int n_nodes = in_sizes[0] / D;
    const int n_edges = in_sizes[1] / 2;
    const int n_label = in_sizes[2] / 2;

    const int* e_src = ei;
    const int* e_dst = ei + n_edges;
    const int* l_src = eli;
    const int* l_dst = eli + n_label;

    // Workspace layout:
    //   bufA   : N*D floats (mean L1 -> mean L2 -> z in place)
    //   h      : N*D floats
    //   deg    : N ints
    //   row_ptr: N+1 ints
    //   cursor : N ints
    //   ssrc   : E ints
    float* bufA   = (float*)d_ws;
    float* h      = bufA + (size_t)n_nodes * D;
    int*   deg    = (int*)(h + (size_t)n_nodes * D);
    int*   rowp   = deg + n_nodes;
    int*   cursor = rowp + (n_nodes + 1);
    int*   ssrc   = cursor + n_nodes;

    dim3 blk(256);
    dim3 grd_edges(2048);
    dim3 grd_nodes(2048);

    const int nscan = (n_nodes + SCAN_BLK - 1) / SCAN_BLK;

    // ---- CSR build (amortized over both layers) ----
    hipMemsetAsync(deg, 0, (size_t)n_nodes * sizeof(int), stream);
    hist_kernel<<<grd_edges, blk, 0, stream>>>(e_dst, deg, n_edges);
    scan1_kernel<<<dim3(nscan), dim3(SCAN_BLK), 0, stream>>>(deg, rowp, cursor /*bsum scratch head*/, n_nodes);
    // NOTE: bsum needs nscan ints; reuse the cursor buffer head (N >= nscan).
    scan2_kernel<<<dim3(1), dim3(128), 0, stream>>>(cursor, nscan);
    scan3_kernel<<<dim3(nscan), dim3(SCAN_BLK), 0, stream>>>(rowp, cursor, n_nodes, n_edges);
    // cursor := row_ptr (running write positions)
    hipMemcpyAsync(cursor, rowp, (size_t)n_nodes * sizeof(int),
                   hipMemcpyDeviceToDevice, stream);
    scatter_ids_kernel<<<grd_edges, blk, 0, stream>>>(e_src, e_dst, cursor, ssrc, n_edges);

    // ---- Layer 1 ----
    aggregate_kernel<<<grd_nodes, blk, 0, stream>>>(x, rowp, ssrc, bufA, n_nodes);
    sage_linear_kernel<<<grd_nodes, blk, 0, stream>>>(bufA, x, W1l, W1r, b1, h,
                                                      n_nodes, /*relu=*/1);

    // ---- Layer 2 ----
    aggregate_kernel<<<grd_nodes, blk, 0, stream>>>(h, rowp, ssrc, bufA, n_nodes);
    sage_linear_kernel<<<grd_nodes, blk, 0, stream>>>(bufA, h, W2l, W2r, b2, bufA,
                                                      n_nodes, /*relu=*/0);

    // ---- Decode ----
    decode_kernel<<<grd_nodes, blk, 0, stream>>>(bufA, l_src, l_dst, out, n_label);
}

// Round 3
// 410.705 us; speedup vs baseline: 2.0556x; 1.3534x over previous
//
#include <hip/hip_runtime.h>

#define D 64
#define SCAN_BLK 1024

// ---------------------------------------------------------------------------
// CSR build step 1: degree histogram (int atomics on cache-resident bins)
// ---------------------------------------------------------------------------
__global__ void hist_kernel(const int* __restrict__ dst, int* __restrict__ deg,
                            int n_edges) {
    int i = blockIdx.x * blockDim.x + threadIdx.x;
    int stride = gridDim.x * blockDim.x;
    for (int e = i; e < n_edges; e += stride) atomicAdd(&deg[dst[e]], 1);
}

// ---------------------------------------------------------------------------
// 3-kernel exclusive scan over deg[n] -> row_ptr[n] (+ row_ptr[n] = n_edges)
// ---------------------------------------------------------------------------
__global__ void scan1_kernel(const int* __restrict__ in, int* __restrict__ out,
                             int* __restrict__ bsum, int n) {
    __shared__ int tmp[SCAN_BLK];
    int gid = blockIdx.x * SCAN_BLK + threadIdx.x;
    int v = (gid < n) ? in[gid] : 0;
    tmp[threadIdx.x] = v;
    __syncthreads();
    for (int off = 1; off < SCAN_BLK; off <<= 1) {
        int t = 0;
        if ((int)threadIdx.x >= off) t = tmp[threadIdx.x - off];
        __syncthreads();
        if ((int)threadIdx.x >= off) tmp[threadIdx.x] += t;
        __syncthreads();
    }
    if (gid < n) out[gid] = tmp[threadIdx.x] - v;  // exclusive
    if (threadIdx.x == SCAN_BLK - 1) bsum[blockIdx.x] = tmp[SCAN_BLK - 1];
}

__global__ void scan2_kernel(int* __restrict__ bsum, int nb) {
    __shared__ int tmp[128];
    int tid = threadIdx.x;
    int v = (tid < nb) ? bsum[tid] : 0;
    tmp[tid] = v;
    __syncthreads();
    for (int off = 1; off < 128; off <<= 1) {
        int t = 0;
        if (tid >= off) t = tmp[tid - off];
        __syncthreads();
        if (tid >= off) tmp[tid] += t;
        __syncthreads();
    }
    if (tid < nb) bsum[tid] = tmp[tid] - v;  // exclusive block offsets
}

__global__ void scan3_kernel(int* __restrict__ out, const int* __restrict__ bsum,
                             int n, int total) {
    int gid = blockIdx.x * SCAN_BLK + threadIdx.x;
    if (gid < n) out[gid] += bsum[blockIdx.x];
    if (gid == 0) out[n] = total;
}

// ---------------------------------------------------------------------------
// CSR build step 3: place each edge's src id into its dst segment.
// ---------------------------------------------------------------------------
__global__ void scatter_ids_kernel(const int* __restrict__ src,
                                   const int* __restrict__ dst,
                                   int* __restrict__ cursor,
                                   int* __restrict__ sorted_src,
                                   int n_edges) {
    int i = blockIdx.x * blockDim.x + threadIdx.x;
    int stride = gridDim.x * blockDim.x;
    for (int e = i; e < n_edges; e += stride) {
        int pos = atomicAdd(&cursor[dst[e]], 1);
        sorted_src[pos] = src[e];
    }
}

// ---------------------------------------------------------------------------
// Mean aggregation: one wave per node, lane d owns feature dim d. No atomics.
// ---------------------------------------------------------------------------
__global__ void aggregate_kernel(const float* __restrict__ feat,
                                 const int* __restrict__ row_ptr,
                                 const int* __restrict__ sorted_src,
                                 float* __restrict__ mean_out,
                                 int n_nodes) {
    int lane   = threadIdx.x & 63;
    int wave   = (int)((blockIdx.x * blockDim.x + threadIdx.x) >> 6);
    int nwaves = (int)((gridDim.x * blockDim.x) >> 6);
    for (int node = wave; node < n_nodes; node += nwaves) {
        int beg = row_ptr[node];
        int end = row_ptr[node + 1];
        float acc = 0.0f;
        int i = beg;
        for (; i + 4 <= end; i += 4) {
            int s0 = sorted_src[i], s1 = sorted_src[i + 1];
            int s2 = sorted_src[i + 2], s3 = sorted_src[i + 3];
            float v0 = feat[(size_t)s0 * D + lane];
            float v1 = feat[(size_t)s1 * D + lane];
            float v2 = feat[(size_t)s2 * D + lane];
            float v3 = feat[(size_t)s3 * D + lane];
            acc += (v0 + v1) + (v2 + v3);
        }
        for (; i < end; ++i) acc += feat[(size_t)sorted_src[i] * D + lane];
        float inv = 1.0f / (float)max(end - beg, 1);
        mean_out[(size_t)node * D + lane] = acc * inv;
    }
}

// ---------------------------------------------------------------------------
// Fused SAGE linear: out = [relu]( mean @ Wl + xin @ Wr + b )
// Register-stationary GEMM: thread = output column (lane), W columns held in
// VGPRs (wl[64]+wr[64]); node rows staged in LDS and consumed as float4
// same-address broadcasts (conflict-free). 2 nodes per wave-iteration for ILP.
// out may alias mean (full row read before row write).
// ---------------------------------------------------------------------------
__global__ __launch_bounds__(256) void sage_linear_kernel(
        const float* __restrict__ mean,
        const float* __restrict__ xin,
        const float* __restrict__ Wl,
        const float* __restrict__ Wr,
        const float* __restrict__ bias,
        float* __restrict__ out,
        int n_nodes, int do_relu) {
    __shared__ float sRow[4][4][D];   // [wave][{m0,x0,m1,x1}][64]

    int lane = threadIdx.x & 63;
    int wid  = threadIdx.x >> 6;

    // W columns into registers (coalesced loads, L2-resident after 1st block)
    float wl[D], wr[D];
#pragma unroll
    for (int k = 0; k < D; ++k) {
        wl[k] = Wl[k * D + lane];
        wr[k] = Wr[k * D + lane];
    }
    float bj = bias[lane];

    int wave   = blockIdx.x * 4 + wid;
    int nwaves = gridDim.x * 4;

    for (int base = wave * 2; base < n_nodes; base += nwaves * 2) {
        int n0 = base;
        int n1 = base + 1;
        bool has1 = (n1 < n_nodes);

        float m0 = mean[(size_t)n0 * D + lane];
        float x0 = xin[(size_t)n0 * D + lane];
        float m1 = has1 ? mean[(size_t)n1 * D + lane] : 0.0f;
        float x1 = has1 ? xin[(size_t)n1 * D + lane] : 0.0f;

        sRow[wid][0][lane] = m0;
        sRow[wid][1][lane] = x0;
        sRow[wid][2][lane] = m1;
        sRow[wid][3][lane] = x1;
        // same-wave LDS RAW: compiler inserts s_waitcnt lgkmcnt before reads

        float acc0 = bj, acc1 = bj;
#pragma unroll
        for (int k4 = 0; k4 < D / 4; ++k4) {
            float4 mv0 = *(const float4*)&sRow[wid][0][k4 * 4];
            float4 xv0 = *(const float4*)&sRow[wid][1][k4 * 4];
            float4 mv1 = *(const float4*)&sRow[wid][2][k4 * 4];
            float4 xv1 = *(const float4*)&sRow[wid][3][k4 * 4];
            acc0 += mv0.x * wl[k4*4+0] + mv0.y * wl[k4*4+1] +
                    mv0.z * wl[k4*4+2] + mv0.w * wl[k4*4+3];
            acc0 += xv0.x * wr[k4*4+0] + xv0.y * wr[k4*4+1] +
                    xv0.z * wr[k4*4+2] + xv0.w * wr[k4*4+3];
            acc1 += mv1.x * wl[k4*4+0] + mv1.y * wl[k4*4+1] +
                    mv1.z * wl[k4*4+2] + mv1.w * wl[k4*4+3];
            acc1 += xv1.x * wr[k4*4+0] + xv1.y * wr[k4*4+1] +
                    xv1.z * wr[k4*4+2] + xv1.w * wr[k4*4+3];
        }
        if (do_relu) { acc0 = fmaxf(acc0, 0.0f); acc1 = fmaxf(acc1, 0.0f); }
        out[(size_t)n0 * D + lane] = acc0;
        if (has1) out[(size_t)n1 * D + lane] = acc1;
    }
}

// ---------------------------------------------------------------------------
// Edge decode: out[e] = dot(z[src_e], z[dst_e]).
// ---------------------------------------------------------------------------
__global__ void decode_kernel(const float* __restrict__ z,
                              const int* __restrict__ esrc,
                              const int* __restrict__ edst,
                              float* __restrict__ out,
                              int n) {
    int lane   = threadIdx.x & 63;
    int wave   = (int)((blockIdx.x * blockDim.x + threadIdx.x) >> 6);
    int nwaves = (int)((gridDim.x * blockDim.x) >> 6);
    for (int e = wave; e < n; e += nwaves) {
        int s  = esrc[e];
        int d0 = edst[e];
        float p = z[(size_t)s * D + lane] * z[(size_t)d0 * D + lane];
#pragma unroll
        for (int off = 32; off > 0; off >>= 1) p += __shfl_down(p, off);
        if (lane == 0) out[e] = p;
    }
}

extern "C" void kernel_launch(void* const* d_in, const int* in_sizes, int n_in,
                              void* d_out, int out_size, void* d_ws, size_t ws_size,
                              hipStream_t stream) {
    const float* x   = (const float*)d_in[0];
    const int*   ei  = (const int*)d_in[1];   // [2, E]: src row then dst row
    const int*   eli = (const int*)d_in[2];   // [2, L]
    const float* W1l = (const float*)d_in[3];
    const float* W1r = (const float*)d_in[4];
    const float* b1  = (const float*)d_in[5];
    const float* W2l = (const float*)d_in[6];
    const float* W2r = (const float*)d_in[7];
    const float* b2  = (const float*)d_in[8];
    float* out = (float*)d_out;

    const int n_nodes = in_sizes[0] / D;
    const int n_edges = in_sizes[1] / 2;
    const int n_label = in_sizes[2] / 2;

    const int* e_src = ei;
    const int* e_dst = ei + n_edges;
    const int* l_src = eli;
    const int* l_dst = eli + n_label;

    // Workspace layout:
    //   bufA   : N*D floats (mean L1 -> mean L2 -> z in place)
    //   h      : N*D floats
    //   deg    : N ints
    //   row_ptr: N+1 ints
    //   cursor : N ints
    //   ssrc   : E ints
    float* bufA   = (float*)d_ws;
    float* h      = bufA + (size_t)n_nodes * D;
    int*   deg    = (int*)(h + (size_t)n_nodes * D);
    int*   rowp   = deg + n_nodes;
    int*   cursor = rowp + (n_nodes + 1);
    int*   ssrc   = cursor + n_nodes;

    dim3 blk(256);
    dim3 grd_edges(2048);
    dim3 grd_nodes(2048);

    const int nscan = (n_nodes + SCAN_BLK - 1) / SCAN_BLK;

    // ---- CSR build (amortized over both layers) ----
    hipMemsetAsync(deg, 0, (size_t)n_nodes * sizeof(int), stream);
    hist_kernel<<<grd_edges, blk, 0, stream>>>(e_dst, deg, n_edges);
    scan1_kernel<<<dim3(nscan), dim3(SCAN_BLK), 0, stream>>>(deg, rowp, cursor, n_nodes);
    scan2_kernel<<<dim3(1), dim3(128), 0, stream>>>(cursor, nscan);
    scan3_kernel<<<dim3(nscan), dim3(SCAN_BLK), 0, stream>>>(rowp, cursor, n_nodes, n_edges);
    hipMemcpyAsync(cursor, rowp, (size_t)n_nodes * sizeof(int),
                   hipMemcpyDeviceToDevice, stream);
    scatter_ids_kernel<<<grd_edges, blk, 0, stream>>>(e_src, e_dst, cursor, ssrc, n_edges);

    // ---- Layer 1 ----
    aggregate_kernel<<<grd_nodes, blk, 0, stream>>>(x, rowp, ssrc, bufA, n_nodes);
    sage_linear_kernel<<<grd_nodes, blk, 0, stream>>>(bufA, x, W1l, W1r, b1, h,
                                                      n_nodes, /*relu=*/1);

    // ---- Layer 2 ----
    aggregate_kernel<<<grd_nodes, blk, 0, stream>>>(h, rowp, ssrc, bufA, n_nodes);
    sage_linear_kernel<<<grd_nodes, blk, 0, stream>>>(bufA, h, W2l, W2r, b2, bufA,
                                                      n_nodes, /*relu=*/0);

    // ---- Decode ----
    decode_kernel<<<grd_nodes, blk, 0, stream>>>(bufA, l_src, l_dst, out, n_label);
}

// Round 4
// 254.928 us; speedup vs baseline: 3.3117x; 1.6111x over previous
//
#include <hip/hip_runtime.h>

#define D 64
#define SCAN_BLK 1024

typedef __attribute__((ext_vector_type(8))) short short8;
typedef __attribute__((ext_vector_type(4))) float f32x4;

__device__ inline unsigned short f2bf(float f) {
    unsigned int u = __float_as_uint(f);
    return (unsigned short)((u + 0x7FFFu + ((u >> 16) & 1u)) >> 16);  // RNE
}
__device__ inline float bf2f(unsigned short s) {
    return __uint_as_float(((unsigned int)s) << 16);
}

// ---------------------------------------------------------------------------
// fp32 -> bf16 bulk convert (x only; everything downstream is produced bf16)
// ---------------------------------------------------------------------------
__global__ void f32_to_bf16_kernel(const float* __restrict__ in,
                                   unsigned short* __restrict__ outp, int n4) {
    int i = blockIdx.x * blockDim.x + threadIdx.x;
    int stride = gridDim.x * blockDim.x;
    for (int t = i; t < n4; t += stride) {
        float4 v = ((const float4*)in)[t];
        ushort4 o;
        o.x = f2bf(v.x); o.y = f2bf(v.y); o.z = f2bf(v.z); o.w = f2bf(v.w);
        ((ushort4*)outp)[t] = o;
    }
}

// ---------------------------------------------------------------------------
// CSR build
// ---------------------------------------------------------------------------
__global__ void hist_kernel(const int* __restrict__ dst, int* __restrict__ deg,
                            int n_edges) {
    int i = blockIdx.x * blockDim.x + threadIdx.x;
    int stride = gridDim.x * blockDim.x;
    for (int e = i; e < n_edges; e += stride) atomicAdd(&deg[dst[e]], 1);
}

__global__ void scan1_kernel(const int* __restrict__ in, int* __restrict__ out,
                             int* __restrict__ bsum, int n) {
    __shared__ int tmp[SCAN_BLK];
    int gid = blockIdx.x * SCAN_BLK + threadIdx.x;
    int v = (gid < n) ? in[gid] : 0;
    tmp[threadIdx.x] = v;
    __syncthreads();
    for (int off = 1; off < SCAN_BLK; off <<= 1) {
        int t = 0;
        if ((int)threadIdx.x >= off) t = tmp[threadIdx.x - off];
        __syncthreads();
        if ((int)threadIdx.x >= off) tmp[threadIdx.x] += t;
        __syncthreads();
    }
    if (gid < n) out[gid] = tmp[threadIdx.x] - v;  // exclusive
    if (threadIdx.x == SCAN_BLK - 1) bsum[blockIdx.x] = tmp[SCAN_BLK - 1];
}

__global__ void scan2_kernel(int* __restrict__ bsum, int nb) {
    __shared__ int tmp[128];
    int tid = threadIdx.x;
    int v = (tid < nb) ? bsum[tid] : 0;
    tmp[tid] = v;
    __syncthreads();
    for (int off = 1; off < 128; off <<= 1) {
        int t = 0;
        if (tid >= off) t = tmp[tid - off];
        __syncthreads();
        if (tid >= off) tmp[tid] += t;
        __syncthreads();
    }
    if (tid < nb) bsum[tid] = tmp[tid] - v;
}

__global__ void scan3_kernel(int* __restrict__ out, const int* __restrict__ bsum,
                             int n, int total) {
    int gid = blockIdx.x * SCAN_BLK + threadIdx.x;
    if (gid < n) out[gid] += bsum[blockIdx.x];
    if (gid == 0) out[n] = total;
}

__global__ void scatter_ids_kernel(const int* __restrict__ src,
                                   const int* __restrict__ dst,
                                   int* __restrict__ cursor,
                                   int* __restrict__ sorted_src,
                                   int n_edges) {
    int i = blockIdx.x * blockDim.x + threadIdx.x;
    int stride = gridDim.x * blockDim.x;
    for (int e = i; e < n_edges; e += stride) {
        int pos = atomicAdd(&cursor[dst[e]], 1);
        sorted_src[pos] = src[e];
    }
}

// ---------------------------------------------------------------------------
// Pack 4 weight matrices [64x64] f32 into MFMA B-fragment order, bf16.
// Fragment addressing per matrix: idx = ((ct*2 + kk)*64 + lane)*8 + j
//   holds W[k = kk*32 + (lane>>4)*8 + j][col = ct*16 + (lane&15)]
// ---------------------------------------------------------------------------
__global__ void pack_w4_kernel(const float* __restrict__ W0,
                               const float* __restrict__ W1,
                               const float* __restrict__ W2,
                               const float* __restrict__ W3,
                               unsigned short* __restrict__ pw) {
    int idx = blockIdx.x * blockDim.x + threadIdx.x;
    if (idx >= 4 * 4096) return;
    int m = idx >> 12;
    int r = idx & 4095;
    const float* W = (m == 0) ? W0 : (m == 1) ? W1 : (m == 2) ? W2 : W3;
    int j    = r & 7;
    int lane = (r >> 3) & 63;
    int kk   = (r >> 9) & 1;
    int ct   = r >> 10;
    int k    = kk * 32 + ((lane >> 4) & 3) * 8 + j;
    int col  = ct * 16 + (lane & 15);
    pw[idx] = f2bf(W[k * D + col]);
}

// ---------------------------------------------------------------------------
// Mean aggregation over bf16 feature rows: wave per node, lane d owns dim d.
// fp32 accumulate, bf16 output row.
// ---------------------------------------------------------------------------
__global__ void aggregate_bf16_kernel(const unsigned short* __restrict__ feat,
                                      const int* __restrict__ row_ptr,
                                      const int* __restrict__ sorted_src,
                                      unsigned short* __restrict__ mean_out,
                                      int n_nodes) {
    int lane   = threadIdx.x & 63;
    int wave   = (int)((blockIdx.x * blockDim.x + threadIdx.x) >> 6);
    int nwaves = (int)((gridDim.x * blockDim.x) >> 6);
    for (int node = wave; node < n_nodes; node += nwaves) {
        int beg = row_ptr[node];
        int end = row_ptr[node + 1];
        float acc = 0.0f;
        int i = beg;
        for (; i + 4 <= end; i += 4) {
            int s0 = sorted_src[i], s1 = sorted_src[i + 1];
            int s2 = sorted_src[i + 2], s3 = sorted_src[i + 3];
            float v0 = bf2f(feat[(size_t)s0 * D + lane]);
            float v1 = bf2f(feat[(size_t)s1 * D + lane]);
            float v2 = bf2f(feat[(size_t)s2 * D + lane]);
            float v3 = bf2f(feat[(size_t)s3 * D + lane]);
            acc += (v0 + v1) + (v2 + v3);
        }
        for (; i < end; ++i) acc += bf2f(feat[(size_t)sorted_src[i] * D + lane]);
        float inv = 1.0f / (float)max(end - beg, 1);
        mean_out[(size_t)node * D + lane] = f2bf(acc * inv);
    }
}

// ---------------------------------------------------------------------------
// Fused SAGE linear on MFMA: out = [relu]( mean @ Wl + xin @ Wr + b ), bf16 io.
// Wave owns a 16-node x 64-col tile. W fragments (packed) live in VGPRs.
// A-fragment: row = lane&15, k = (lane>>4)*8 + j  (16B contiguous load).
// C/D: col = lane&15, row = (lane>>4)*4 + reg  (m89-verified).
// ---------------------------------------------------------------------------
__global__ __launch_bounds__(256) void sage_linear_mfma_kernel(
        const unsigned short* __restrict__ mean,
        const unsigned short* __restrict__ xin,
        const unsigned short* __restrict__ pwl,
        const unsigned short* __restrict__ pwr,
        const float* __restrict__ bias,
        unsigned short* __restrict__ outp,
        int n_nodes, int do_relu) {
    int lane = threadIdx.x & 63;
    int wid  = threadIdx.x >> 6;
    int arow = lane & 15;
    int kgrp = lane >> 4;

    // Weight fragments: 4 col-tiles x 2 k-halves x 16B, per matrix = 64 VGPRs
    short8 wl[4][2], wr[4][2];
#pragma unroll
    for (int ct = 0; ct < 4; ++ct)
#pragma unroll
        for (int kk = 0; kk < 2; ++kk) {
            wl[ct][kk] = *(const short8*)(pwl + (((ct * 2 + kk) * 64 + lane) << 3));
            wr[ct][kk] = *(const short8*)(pwr + (((ct * 2 + kk) * 64 + lane) << 3));
        }
    float bj[4];
#pragma unroll
    for (int ct = 0; ct < 4; ++ct) bj[ct] = bias[ct * 16 + arow];

    int wave   = blockIdx.x * 4 + wid;
    int nwaves = gridDim.x * 4;
    int ntiles = (n_nodes + 15) >> 4;

    for (int t = wave; t < ntiles; t += nwaves) {
        int base = t * 16;
        int lrow = base + arow;
        if (lrow >= n_nodes) lrow = n_nodes - 1;  // clamp (stores guarded)
        const unsigned short* mrow = mean + (size_t)lrow * D + kgrp * 8;
        const unsigned short* xrow = xin  + (size_t)lrow * D + kgrp * 8;
        short8 am0 = *(const short8*)(mrow);
        short8 am1 = *(const short8*)(mrow + 32);
        short8 ax0 = *(const short8*)(xrow);
        short8 ax1 = *(const short8*)(xrow + 32);

#pragma unroll
        for (int ct = 0; ct < 4; ++ct) {
            f32x4 acc = {0.f, 0.f, 0.f, 0.f};
            acc = __builtin_amdgcn_mfma_f32_16x16x32_bf16(am0, wl[ct][0], acc, 0, 0, 0);
            acc = __builtin_amdgcn_mfma_f32_16x16x32_bf16(am1, wl[ct][1], acc, 0, 0, 0);
            acc = __builtin_amdgcn_mfma_f32_16x16x32_bf16(ax0, wr[ct][0], acc, 0, 0, 0);
            acc = __builtin_amdgcn_mfma_f32_16x16x32_bf16(ax1, wr[ct][1], acc, 0, 0, 0);
            int col = ct * 16 + arow;
#pragma unroll
            for (int r = 0; r < 4; ++r) {
                int row = base + kgrp * 4 + r;
                float v = acc[r] + bj[ct];
                if (do_relu) v = fmaxf(v, 0.0f);
                if (row < n_nodes) outp[(size_t)row * D + col] = f2bf(v);
            }
        }
    }
}

// ---------------------------------------------------------------------------
// Edge decode on bf16 z: out[e] = dot(z[src_e], z[dst_e]) in fp32.
// ---------------------------------------------------------------------------
__global__ void decode_bf16_kernel(const unsigned short* __restrict__ z,
                                   const int* __restrict__ esrc,
                                   const int* __restrict__ edst,
                                   float* __restrict__ out,
                                   int n) {
    int lane   = threadIdx.x & 63;
    int wave   = (int)((blockIdx.x * blockDim.x + threadIdx.x) >> 6);
    int nwaves = (int)((gridDim.x * blockDim.x) >> 6);
    for (int e = wave; e < n; e += nwaves) {
        int s  = esrc[e];
        int d0 = edst[e];
        float p = bf2f(z[(size_t)s * D + lane]) * bf2f(z[(size_t)d0 * D + lane]);
#pragma unroll
        for (int off = 32; off > 0; off >>= 1) p += __shfl_down(p, off);
        if (lane == 0) out[e] = p;
    }
}

extern "C" void kernel_launch(void* const* d_in, const int* in_sizes, int n_in,
                              void* d_out, int out_size, void* d_ws, size_t ws_size,
                              hipStream_t stream) {
    const float* x   = (const float*)d_in[0];
    const int*   ei  = (const int*)d_in[1];   // [2, E]: src row then dst row
    const int*   eli = (const int*)d_in[2];   // [2, L]
    const float* W1l = (const float*)d_in[3];
    const float* W1r = (const float*)d_in[4];
    const float* b1  = (const float*)d_in[5];
    const float* W2l = (const float*)d_in[6];
    const float* W2r = (const float*)d_in[7];
    const float* b2  = (const float*)d_in[8];
    float* out = (float*)d_out;

    const int n_nodes = in_sizes[0] / D;
    const int n_edges = in_sizes[1] / 2;
    const int n_label = in_sizes[2] / 2;

    const int* e_src = ei;
    const int* e_dst = ei + n_edges;
    const int* l_src = eli;
    const int* l_dst = eli + n_label;

    // Workspace layout (bf16 features):
    //   xb, meanb, h, z : N*64 ushort each
    //   deg, rowp(N+1), cursor : ints
    //   ssrc : E ints
    //   pw   : 4*4096 ushort (packed weights)
    unsigned short* xb    = (unsigned short*)d_ws;
    unsigned short* meanb = xb + (size_t)n_nodes * D;
    unsigned short* h     = meanb + (size_t)n_nodes * D;
    unsigned short* z     = h + (size_t)n_nodes * D;
    int* deg    = (int*)(z + (size_t)n_nodes * D);
    int* rowp   = deg + n_nodes;
    int* cursor = rowp + (n_nodes + 1);
    int* ssrc   = cursor + n_nodes;
    unsigned short* pw = (unsigned short*)(ssrc + n_edges);
    unsigned short* pw1l = pw;
    unsigned short* pw1r = pw + 4096;
    unsigned short* pw2l = pw + 8192;
    unsigned short* pw2r = pw + 12288;

    dim3 blk(256);
    dim3 grd_edges(2048);
    dim3 grd_nodes(2048);
    dim3 grd_linear(512);

    const int nscan = (n_nodes + SCAN_BLK - 1) / SCAN_BLK;

    // ---- Input convert + CSR build ----
    f32_to_bf16_kernel<<<grd_nodes, blk, 0, stream>>>(x, xb, n_nodes * D / 4);
    hipMemsetAsync(deg, 0, (size_t)n_nodes * sizeof(int), stream);
    hist_kernel<<<grd_edges, blk, 0, stream>>>(e_dst, deg, n_edges);
    scan1_kernel<<<dim3(nscan), dim3(SCAN_BLK), 0, stream>>>(deg, rowp, cursor, n_nodes);
    scan2_kernel<<<dim3(1), dim3(128), 0, stream>>>(cursor, nscan);
    scan3_kernel<<<dim3(nscan), dim3(SCAN_BLK), 0, stream>>>(rowp, cursor, n_nodes, n_edges);
    hipMemcpyAsync(cursor, rowp, (size_t)n_nodes * sizeof(int),
                   hipMemcpyDeviceToDevice, stream);
    scatter_ids_kernel<<<grd_edges, blk, 0, stream>>>(e_src, e_dst, cursor, ssrc, n_edges);
    pack_w4_kernel<<<dim3(64), blk, 0, stream>>>(W1l, W1r, W2l, W2r, pw);

    // ---- Layer 1 ----
    aggregate_bf16_kernel<<<grd_nodes, blk, 0, stream>>>(xb, rowp, ssrc, meanb, n_nodes);
    sage_linear_mfma_kernel<<<grd_linear, blk, 0, stream>>>(meanb, xb, pw1l, pw1r, b1,
                                                            h, n_nodes, /*relu=*/1);

    // ---- Layer 2 ----
    aggregate_bf16_kernel<<<grd_nodes, blk, 0, stream>>>(h, rowp, ssrc, meanb, n_nodes);
    sage_linear_mfma_kernel<<<grd_linear, blk, 0, stream>>>(meanb, h, pw2l, pw2r, b2,
                                                            z, n_nodes, /*relu=*/0);

    // ---- Decode ----
    decode_bf16_kernel<<<grd_nodes, blk, 0, stream>>>(z, l_src, l_dst, out, n_label);
}

// Round 5
// 181.477 us; speedup vs baseline: 4.6521x; 1.4047x over previous
//
#include <hip/hip_runtime.h>

#define D 64
#define NB_SHIFT 9          // 512 nodes per bucket
#define NODES_PER_B 512
#define CAP1 12288          // max edges per bucket (mean ~5120, +100 sigma)

typedef __attribute__((ext_vector_type(8))) short short8;
typedef __attribute__((ext_vector_type(4))) float f32x4;

__device__ inline unsigned short f2bf(float f) {
    unsigned int u = __float_as_uint(f);
    return (unsigned short)((u + 0x7FFFu + ((u >> 16) & 1u)) >> 16);  // RNE
}
__device__ inline float bf2f(unsigned short s) {
    return __uint_as_float(((unsigned int)s) << 16);
}

// ---------------------------------------------------------------------------
// fp32 -> bf16 bulk convert
// ---------------------------------------------------------------------------
__global__ void f32_to_bf16_kernel(const float* __restrict__ in,
                                   unsigned short* __restrict__ outp, int n4) {
    int i = blockIdx.x * blockDim.x + threadIdx.x;
    int stride = gridDim.x * blockDim.x;
    for (int t = i; t < n4; t += stride) {
        float4 v = ((const float4*)in)[t];
        ushort4 o;
        o.x = f2bf(v.x); o.y = f2bf(v.y); o.z = f2bf(v.z); o.w = f2bf(v.w);
        ((ushort4*)outp)[t] = o;
    }
}

// ---------------------------------------------------------------------------
// Pass 1: bin edges by dst bucket (dst>>9). Per-block LDS histogram, one
// global reservation atomic per (block,bucket), then contiguous-run writes of
// (src,dst) pairs into fixed-capacity bucket regions.
// ---------------------------------------------------------------------------
__global__ __launch_bounds__(256) void bin_edges_kernel(
        const int* __restrict__ src, const int* __restrict__ dst,
        int* __restrict__ gcount, int2* __restrict__ binned,
        int n_edges, int n_buckets) {
    __shared__ int lhist[256];
    __shared__ int lbase[256];
    int tid = threadIdx.x;
    int per = (n_edges + gridDim.x - 1) / gridDim.x;
    int beg = blockIdx.x * per;
    int end = min(beg + per, n_edges);

    lhist[tid] = 0;
    __syncthreads();
    for (int e = beg + tid; e < end; e += 256)
        atomicAdd(&lhist[dst[e] >> NB_SHIFT], 1);
    __syncthreads();
    if (tid < n_buckets && lhist[tid] > 0)
        lbase[tid] = atomicAdd(&gcount[tid], lhist[tid]);
    else
        lbase[tid] = 0;
    __syncthreads();
    lhist[tid] = 0;   // reuse as running cursor
    __syncthreads();
    for (int e = beg + tid; e < end; e += 256) {
        int d = dst[e];
        int b = d >> NB_SHIFT;
        int off = lbase[b] + atomicAdd(&lhist[b], 1);
        if (off < CAP1)  // defensive; cannot trigger for this distribution
            binned[(size_t)b * CAP1 + off] = make_int2(src[e], d);
    }
}

// ---------------------------------------------------------------------------
// Exclusive scan over bucket counts -> bucket bases; also rowp[N] = E.
// One block; n_buckets <= 256.
// ---------------------------------------------------------------------------
__global__ __launch_bounds__(256) void bucket_scan_kernel(
        const int* __restrict__ gcount, int* __restrict__ gbase,
        int* __restrict__ rowp, int n_buckets, int n_nodes, int n_edges) {
    __shared__ int tmp[256];
    int tid = threadIdx.x;
    int v = (tid < n_buckets) ? min(gcount[tid], CAP1) : 0;
    tmp[tid] = v;
    __syncthreads();
    for (int off = 1; off < 256; off <<= 1) {
        int t = 0;
        if (tid >= off) t = tmp[tid - off];
        __syncthreads();
        if (tid >= off) tmp[tid] += t;
        __syncthreads();
    }
    if (tid < n_buckets) gbase[tid] = tmp[tid] - v;  // exclusive
    if (tid == 0) rowp[n_nodes] = n_edges;
}

// ---------------------------------------------------------------------------
// Pass 2: one block per bucket. Local degree histogram over 512 nodes ->
// LDS scan -> coalesced rowp writes -> place srcs into LDS staging ->
// coalesced flush to ssrc.
// ---------------------------------------------------------------------------
__global__ __launch_bounds__(256) void build_csr_kernel(
        const int2* __restrict__ binned, const int* __restrict__ gcount,
        const int* __restrict__ gbase, int* __restrict__ rowp,
        int* __restrict__ ssrc, int n_nodes) {
    __shared__ int lhist[NODES_PER_B];
    __shared__ int lbase[NODES_PER_B];
    __shared__ int tmp[256];
    __shared__ int stage[CAP1];

    int b        = blockIdx.x;
    int tid      = threadIdx.x;
    int nodebase = b << NB_SHIFT;
    int nlocal   = min(NODES_PER_B, n_nodes - nodebase);
    int cnt      = min(gcount[b], CAP1);
    int base     = gbase[b];
    const int2* ebuf = binned + (size_t)b * CAP1;

    lhist[tid] = 0;
    lhist[tid + 256] = 0;
    __syncthreads();
    for (int i = tid; i < cnt; i += 256)
        atomicAdd(&lhist[ebuf[i].y - nodebase], 1);
    __syncthreads();

    // exclusive scan over 512 bins: thread t owns bins {2t, 2t+1}
    int a0 = lhist[2 * tid];
    int a1 = lhist[2 * tid + 1];
    tmp[tid] = a0 + a1;
    __syncthreads();
    for (int off = 1; off < 256; off <<= 1) {
        int t = 0;
        if (tid >= off) t = tmp[tid - off];
        __syncthreads();
        if (tid >= off) tmp[tid] += t;
        __syncthreads();
    }
    int excl = tmp[tid] - (a0 + a1);
    lbase[2 * tid]     = excl;
    lbase[2 * tid + 1] = excl + a0;
    __syncthreads();

    // rowp (coalesced)
    for (int j = tid; j < nlocal; j += 256)
        rowp[nodebase + j] = base + lbase[j];

    // reset lhist as per-node cursors
    lhist[tid] = 0;
    lhist[tid + 256] = 0;
    __syncthreads();

    // place into LDS staging
    for (int i = tid; i < cnt; i += 256) {
        int2 e = ebuf[i];
        int ln = e.y - nodebase;
        int off = atomicAdd(&lhist[ln], 1);
        stage[lbase[ln] + off] = e.x;
    }
    __syncthreads();

    // coalesced flush
    for (int i = tid; i < cnt; i += 256)
        ssrc[base + i] = stage[i];
}

// ---------------------------------------------------------------------------
// Pack 4 weight matrices [64x64] f32 into MFMA B-fragment order, bf16.
// idx = ((ct*2 + kk)*64 + lane)*8 + j holds
//   W[k = kk*32 + (lane>>4)*8 + j][col = ct*16 + (lane&15)]
// ---------------------------------------------------------------------------
__global__ void pack_w4_kernel(const float* __restrict__ W0,
                               const float* __restrict__ W1,
                               const float* __restrict__ W2,
                               const float* __restrict__ W3,
                               unsigned short* __restrict__ pw) {
    int idx = blockIdx.x * blockDim.x + threadIdx.x;
    if (idx >= 4 * 4096) return;
    int m = idx >> 12;
    int r = idx & 4095;
    const float* W = (m == 0) ? W0 : (m == 1) ? W1 : (m == 2) ? W2 : W3;
    int j    = r & 7;
    int lane = (r >> 3) & 63;
    int kk   = (r >> 9) & 1;
    int ct   = r >> 10;
    int k    = kk * 32 + ((lane >> 4) & 3) * 8 + j;
    int col  = ct * 16 + (lane & 15);
    pw[idx] = f2bf(W[k * D + col]);
}

// ---------------------------------------------------------------------------
// Mean aggregation over bf16 feature rows: wave per node, lane d owns dim d.
// ---------------------------------------------------------------------------
__global__ void aggregate_bf16_kernel(const unsigned short* __restrict__ feat,
                                      const int* __restrict__ row_ptr,
                                      const int* __restrict__ sorted_src,
                                      unsigned short* __restrict__ mean_out,
                                      int n_nodes) {
    int lane   = threadIdx.x & 63;
    int wave   = (int)((blockIdx.x * blockDim.x + threadIdx.x) >> 6);
    int nwaves = (int)((gridDim.x * blockDim.x) >> 6);
    for (int node = wave; node < n_nodes; node += nwaves) {
        int beg = row_ptr[node];
        int end = row_ptr[node + 1];
        float acc = 0.0f;
        int i = beg;
        for (; i + 4 <= end; i += 4) {
            int s0 = sorted_src[i], s1 = sorted_src[i + 1];
            int s2 = sorted_src[i + 2], s3 = sorted_src[i + 3];
            float v0 = bf2f(feat[(size_t)s0 * D + lane]);
            float v1 = bf2f(feat[(size_t)s1 * D + lane]);
            float v2 = bf2f(feat[(size_t)s2 * D + lane]);
            float v3 = bf2f(feat[(size_t)s3 * D + lane]);
            acc += (v0 + v1) + (v2 + v3);
        }
        for (; i < end; ++i) acc += bf2f(feat[(size_t)sorted_src[i] * D + lane]);
        float inv = 1.0f / (float)max(end - beg, 1);
        mean_out[(size_t)node * D + lane] = f2bf(acc * inv);
    }
}

// ---------------------------------------------------------------------------
// Fused SAGE linear on MFMA: out = [relu]( mean @ Wl + xin @ Wr + b ), bf16 io.
// ---------------------------------------------------------------------------
__global__ __launch_bounds__(256) void sage_linear_mfma_kernel(
        const unsigned short* __restrict__ mean,
        const unsigned short* __restrict__ xin,
        const unsigned short* __restrict__ pwl,
        const unsigned short* __restrict__ pwr,
        const float* __restrict__ bias,
        unsigned short* __restrict__ outp,
        int n_nodes, int do_relu) {
    int lane = threadIdx.x & 63;
    int wid  = threadIdx.x >> 6;
    int arow = lane & 15;
    int kgrp = lane >> 4;

    short8 wl[4][2], wr[4][2];
#pragma unroll
    for (int ct = 0; ct < 4; ++ct)
#pragma unroll
        for (int kk = 0; kk < 2; ++kk) {
            wl[ct][kk] = *(const short8*)(pwl + (((ct * 2 + kk) * 64 + lane) << 3));
            wr[ct][kk] = *(const short8*)(pwr + (((ct * 2 + kk) * 64 + lane) << 3));
        }
    float bj[4];
#pragma unroll
    for (int ct = 0; ct < 4; ++ct) bj[ct] = bias[ct * 16 + arow];

    int wave   = blockIdx.x * 4 + wid;
    int nwaves = gridDim.x * 4;
    int ntiles = (n_nodes + 15) >> 4;

    for (int t = wave; t < ntiles; t += nwaves) {
        int base = t * 16;
        int lrow = base + arow;
        if (lrow >= n_nodes) lrow = n_nodes - 1;
        const unsigned short* mrow = mean + (size_t)lrow * D + kgrp * 8;
        const unsigned short* xrow = xin  + (size_t)lrow * D + kgrp * 8;
        short8 am0 = *(const short8*)(mrow);
        short8 am1 = *(const short8*)(mrow + 32);
        short8 ax0 = *(const short8*)(xrow);
        short8 ax1 = *(const short8*)(xrow + 32);

#pragma unroll
        for (int ct = 0; ct < 4; ++ct) {
            f32x4 acc = {0.f, 0.f, 0.f, 0.f};
            acc = __builtin_amdgcn_mfma_f32_16x16x32_bf16(am0, wl[ct][0], acc, 0, 0, 0);
            acc = __builtin_amdgcn_mfma_f32_16x16x32_bf16(am1, wl[ct][1], acc, 0, 0, 0);
            acc = __builtin_amdgcn_mfma_f32_16x16x32_bf16(ax0, wr[ct][0], acc, 0, 0, 0);
            acc = __builtin_amdgcn_mfma_f32_16x16x32_bf16(ax1, wr[ct][1], acc, 0, 0, 0);
            int col = ct * 16 + arow;
#pragma unroll
            for (int r = 0; r < 4; ++r) {
                int row = base + kgrp * 4 + r;
                float v = acc[r] + bj[ct];
                if (do_relu) v = fmaxf(v, 0.0f);
                if (row < n_nodes) outp[(size_t)row * D + col] = f2bf(v);
            }
        }
    }
}

// ---------------------------------------------------------------------------
// Edge decode on bf16 z: out[e] = dot(z[src_e], z[dst_e]) in fp32.
// ---------------------------------------------------------------------------
__global__ void decode_bf16_kernel(const unsigned short* __restrict__ z,
                                   const int* __restrict__ esrc,
                                   const int* __restrict__ edst,
                                   float* __restrict__ out,
                                   int n) {
    int lane   = threadIdx.x & 63;
    int wave   = (int)((blockIdx.x * blockDim.x + threadIdx.x) >> 6);
    int nwaves = (int)((gridDim.x * blockDim.x) >> 6);
    for (int e = wave; e < n; e += nwaves) {
        int s  = esrc[e];
        int d0 = edst[e];
        float p = bf2f(z[(size_t)s * D + lane]) * bf2f(z[(size_t)d0 * D + lane]);
#pragma unroll
        for (int off = 32; off > 0; off >>= 1) p += __shfl_down(p, off);
        if (lane == 0) out[e] = p;
    }
}

extern "C" void kernel_launch(void* const* d_in, const int* in_sizes, int n_in,
                              void* d_out, int out_size, void* d_ws, size_t ws_size,
                              hipStream_t stream) {
    const float* x   = (const float*)d_in[0];
    const int*   ei  = (const int*)d_in[1];   // [2, E]: src row then dst row
    const int*   eli = (const int*)d_in[2];   // [2, L]
    const float* W1l = (const float*)d_in[3];
    const float* W1r = (const float*)d_in[4];
    const float* b1  = (const float*)d_in[5];
    const float* W2l = (const float*)d_in[6];
    const float* W2r = (const float*)d_in[7];
    const float* b2  = (const float*)d_in[8];
    float* out = (float*)d_out;

    const int n_nodes = in_sizes[0] / D;
    const int n_edges = in_sizes[1] / 2;
    const int n_label = in_sizes[2] / 2;
    const int n_buckets = (n_nodes + NODES_PER_B - 1) >> NB_SHIFT;

    const int* e_src = ei;
    const int* e_dst = ei + n_edges;
    const int* l_src = eli;
    const int* l_dst = eli + n_label;

    // Workspace layout:
    //   xb, meanb, h, z : N*64 ushort each (12.8 MB each)
    //   rowp  : N+1 ints
    //   ssrc  : E ints
    //   gcount, gbase : 256 ints each
    //   pw    : 4*4096 ushort
    //   binned: aliases h..z (19.3 MB <= 25.6 MB), dead before h first written
    unsigned short* xb    = (unsigned short*)d_ws;
    unsigned short* meanb = xb + (size_t)n_nodes * D;
    unsigned short* h     = meanb + (size_t)n_nodes * D;
    unsigned short* z     = h + (size_t)n_nodes * D;
    int* rowp   = (int*)(z + (size_t)n_nodes * D);
    int* ssrc   = rowp + (n_nodes + 1);
    int* gcount = ssrc + n_edges;
    int* gbase  = gcount + 256;
    unsigned short* pw = (unsigned short*)(gbase + 256);
    unsigned short* pw1l = pw;
    unsigned short* pw1r = pw + 4096;
    unsigned short* pw2l = pw + 8192;
    unsigned short* pw2r = pw + 12288;
    int2* binned = (int2*)h;

    dim3 blk(256);
    dim3 grd_nodes(2048);
    dim3 grd_linear(512);

    // ---- Input convert + weight pack ----
    f32_to_bf16_kernel<<<grd_nodes, blk, 0, stream>>>(x, xb, n_nodes * D / 4);
    pack_w4_kernel<<<dim3(64), blk, 0, stream>>>(W1l, W1r, W2l, W2r, pw);

    // ---- CSR build: bin -> scan -> per-bucket build ----
    hipMemsetAsync(gcount, 0, 256 * sizeof(int), stream);
    bin_edges_kernel<<<dim3(512), blk, 0, stream>>>(e_src, e_dst, gcount, binned,
                                                    n_edges, n_buckets);
    bucket_scan_kernel<<<dim3(1), blk, 0, stream>>>(gcount, gbase, rowp,
                                                    n_buckets, n_nodes, n_edges);
    build_csr_kernel<<<dim3(n_buckets), blk, 0, stream>>>(binned, gcount, gbase,
                                                          rowp, ssrc, n_nodes);

    // ---- Layer 1 ----
    aggregate_bf16_kernel<<<grd_nodes, blk, 0, stream>>>(xb, rowp, ssrc, meanb, n_nodes);
    sage_linear_mfma_kernel<<<grd_linear, blk, 0, stream>>>(meanb, xb, pw1l, pw1r, b1,
                                                            h, n_nodes, /*relu=*/1);

    // ---- Layer 2 ----
    aggregate_bf16_kernel<<<grd_nodes, blk, 0, stream>>>(h, rowp, ssrc, meanb, n_nodes);
    sage_linear_mfma_kernel<<<grd_linear, blk, 0, stream>>>(meanb, h, pw2l, pw2r, b2,
                                                            z, n_nodes, /*relu=*/0);

    // ---- Decode ----
    decode_bf16_kernel<<<grd_nodes, blk, 0, stream>>>(z, l_src, l_dst, out, n_label);
}

// Round 6
// 156.364 us; speedup vs baseline: 5.3992x; 1.1606x over previous
//
#include <hip/hip_runtime.h>

#define D 64
#define NB_SHIFT 9          // 512 nodes per bucket
#define NODES_PER_B 512
#define CAP1 12288          // max edges per bucket (mean ~5120)

typedef __attribute__((ext_vector_type(8))) short short8;
typedef __attribute__((ext_vector_type(4))) float f32x4;

__device__ inline unsigned short f2bf(float f) {
    unsigned int u = __float_as_uint(f);
    return (unsigned short)((u + 0x7FFFu + ((u >> 16) & 1u)) >> 16);  // RNE
}
__device__ inline float bf2f(unsigned short s) {
    return __uint_as_float(((unsigned int)s) << 16);
}

// ---------------------------------------------------------------------------
// fp32 -> bf16 bulk convert
// ---------------------------------------------------------------------------
__global__ void f32_to_bf16_kernel(const float* __restrict__ in,
                                   unsigned short* __restrict__ outp, int n4) {
    int i = blockIdx.x * blockDim.x + threadIdx.x;
    int stride = gridDim.x * blockDim.x;
    for (int t = i; t < n4; t += stride) {
        float4 v = ((const float4*)in)[t];
        ushort4 o;
        o.x = f2bf(v.x); o.y = f2bf(v.y); o.z = f2bf(v.z); o.w = f2bf(v.w);
        ((ushort4*)outp)[t] = o;
    }
}

// ---------------------------------------------------------------------------
// Pass 1: bin edges by dst bucket (dst>>9).
// ---------------------------------------------------------------------------
__global__ __launch_bounds__(256) void bin_edges_kernel(
        const int* __restrict__ src, const int* __restrict__ dst,
        int* __restrict__ gcount, int2* __restrict__ binned,
        int n_edges, int n_buckets) {
    __shared__ int lhist[256];
    __shared__ int lbase[256];
    int tid = threadIdx.x;
    int per = (n_edges + gridDim.x - 1) / gridDim.x;
    int beg = blockIdx.x * per;
    int end = min(beg + per, n_edges);

    lhist[tid] = 0;
    __syncthreads();
    for (int e = beg + tid; e < end; e += 256)
        atomicAdd(&lhist[dst[e] >> NB_SHIFT], 1);
    __syncthreads();
    if (tid < n_buckets && lhist[tid] > 0)
        lbase[tid] = atomicAdd(&gcount[tid], lhist[tid]);
    else
        lbase[tid] = 0;
    __syncthreads();
    lhist[tid] = 0;   // reuse as running cursor
    __syncthreads();
    for (int e = beg + tid; e < end; e += 256) {
        int d = dst[e];
        int b = d >> NB_SHIFT;
        int off = lbase[b] + atomicAdd(&lhist[b], 1);
        if (off < CAP1)
            binned[(size_t)b * CAP1 + off] = make_int2(src[e], d);
    }
}

// ---------------------------------------------------------------------------
// Exclusive scan over bucket counts; rowp[N] = E.
// ---------------------------------------------------------------------------
__global__ __launch_bounds__(256) void bucket_scan_kernel(
        const int* __restrict__ gcount, int* __restrict__ gbase,
        int* __restrict__ rowp, int n_buckets, int n_nodes, int n_edges) {
    __shared__ int tmp[256];
    int tid = threadIdx.x;
    int v = (tid < n_buckets) ? min(gcount[tid], CAP1) : 0;
    tmp[tid] = v;
    __syncthreads();
    for (int off = 1; off < 256; off <<= 1) {
        int t = 0;
        if (tid >= off) t = tmp[tid - off];
        __syncthreads();
        if (tid >= off) tmp[tid] += t;
        __syncthreads();
    }
    if (tid < n_buckets) gbase[tid] = tmp[tid] - v;
    if (tid == 0) rowp[n_nodes] = n_edges;
}

// ---------------------------------------------------------------------------
// Pass 2: one block per bucket -> rowp + ssrc (coalesced).
// ---------------------------------------------------------------------------
__global__ __launch_bounds__(256) void build_csr_kernel(
        const int2* __restrict__ binned, const int* __restrict__ gcount,
        const int* __restrict__ gbase, int* __restrict__ rowp,
        int* __restrict__ ssrc, int n_nodes) {
    __shared__ int lhist[NODES_PER_B];
    __shared__ int lbase[NODES_PER_B];
    __shared__ int tmp[256];
    __shared__ int stage[CAP1];

    int b        = blockIdx.x;
    int tid      = threadIdx.x;
    int nodebase = b << NB_SHIFT;
    int nlocal   = min(NODES_PER_B, n_nodes - nodebase);
    int cnt      = min(gcount[b], CAP1);
    int base     = gbase[b];
    const int2* ebuf = binned + (size_t)b * CAP1;

    lhist[tid] = 0;
    lhist[tid + 256] = 0;
    __syncthreads();
    for (int i = tid; i < cnt; i += 256)
        atomicAdd(&lhist[ebuf[i].y - nodebase], 1);
    __syncthreads();

    int a0 = lhist[2 * tid];
    int a1 = lhist[2 * tid + 1];
    tmp[tid] = a0 + a1;
    __syncthreads();
    for (int off = 1; off < 256; off <<= 1) {
        int t = 0;
        if (tid >= off) t = tmp[tid - off];
        __syncthreads();
        if (tid >= off) tmp[tid] += t;
        __syncthreads();
    }
    int excl = tmp[tid] - (a0 + a1);
    lbase[2 * tid]     = excl;
    lbase[2 * tid + 1] = excl + a0;
    __syncthreads();

    for (int j = tid; j < nlocal; j += 256)
        rowp[nodebase + j] = base + lbase[j];

    lhist[tid] = 0;
    lhist[tid + 256] = 0;
    __syncthreads();

    for (int i = tid; i < cnt; i += 256) {
        int2 e = ebuf[i];
        int ln = e.y - nodebase;
        int off = atomicAdd(&lhist[ln], 1);
        stage[lbase[ln] + off] = e.x;
    }
    __syncthreads();

    for (int i = tid; i < cnt; i += 256)
        ssrc[base + i] = stage[i];
}

// ---------------------------------------------------------------------------
// Pack 4 weight matrices into MFMA B-fragment order, bf16.
// ---------------------------------------------------------------------------
__global__ void pack_w4_kernel(const float* __restrict__ W0,
                               const float* __restrict__ W1,
                               const float* __restrict__ W2,
                               const float* __restrict__ W3,
                               unsigned short* __restrict__ pw) {
    int idx = blockIdx.x * blockDim.x + threadIdx.x;
    if (idx >= 4 * 4096) return;
    int m = idx >> 12;
    int r = idx & 4095;
    const float* W = (m == 0) ? W0 : (m == 1) ? W1 : (m == 2) ? W2 : W3;
    int j    = r & 7;
    int lane = (r >> 3) & 63;
    int kk   = (r >> 9) & 1;
    int ct   = r >> 10;
    int k    = kk * 32 + ((lane >> 4) & 3) * 8 + j;
    int col  = ct * 16 + (lane & 15);
    pw[idx] = f2bf(W[k * D + col]);
}

// ---------------------------------------------------------------------------
// Mean aggregation v2: wave per node; lane = (row r = lane>>4, dim-quad
// c = lane&15). Each iteration gathers 8 edges via 2 dwordx2 loads/lane
// (4 rows x 128B per load instruction). fp32 acc[4]; butterfly over masks
// 16/32; 16 lanes write the bf16 row (ushort4).
// ---------------------------------------------------------------------------
__global__ __launch_bounds__(256) void aggregate_bf16_kernel(
        const unsigned short* __restrict__ feat,
        const int* __restrict__ row_ptr,
        const int* __restrict__ sorted_src,
        unsigned short* __restrict__ mean_out,
        int n_nodes) {
    int lane = threadIdx.x & 63;
    int r    = lane >> 4;        // row within 4-row gather group
    int c    = lane & 15;        // dim quad: dims c*4..c*4+3
    int wave   = (int)((blockIdx.x * blockDim.x + threadIdx.x) >> 6);
    int nwaves = (int)((gridDim.x * blockDim.x) >> 6);

    for (int node = wave; node < n_nodes; node += nwaves) {
        int beg = row_ptr[node];
        int end = row_ptr[node + 1];
        int endm1 = end - 1;
        float a0 = 0.f, a1 = 0.f, a2 = 0.f, a3 = 0.f;

        for (int i = beg; i < end; i += 8) {
            int e0 = i + r;
            int e1 = i + 4 + r;
            int s0 = sorted_src[min(e0, endm1)];
            int s1 = sorted_src[min(e1, endm1)];
            ushort4 v0 = *(const ushort4*)(feat + ((size_t)s0 << 6) + (c << 2));
            ushort4 v1 = *(const ushort4*)(feat + ((size_t)s1 << 6) + (c << 2));
            if (e0 < end) {
                a0 += bf2f(v0.x); a1 += bf2f(v0.y);
                a2 += bf2f(v0.z); a3 += bf2f(v0.w);
            }
            if (e1 < end) {
                a0 += bf2f(v1.x); a1 += bf2f(v1.y);
                a2 += bf2f(v1.z); a3 += bf2f(v1.w);
            }
        }
        // combine the 4 row-groups: lanes l, l^16, l^32, l^48
        a0 += __shfl_xor(a0, 16); a1 += __shfl_xor(a1, 16);
        a2 += __shfl_xor(a2, 16); a3 += __shfl_xor(a3, 16);
        a0 += __shfl_xor(a0, 32); a1 += __shfl_xor(a1, 32);
        a2 += __shfl_xor(a2, 32); a3 += __shfl_xor(a3, 32);

        float inv = 1.0f / (float)max(end - beg, 1);
        if (r == 0) {
            ushort4 o;
            o.x = f2bf(a0 * inv); o.y = f2bf(a1 * inv);
            o.z = f2bf(a2 * inv); o.w = f2bf(a3 * inv);
            *(ushort4*)(mean_out + ((size_t)node << 6) + (c << 2)) = o;
        }
    }
}

// ---------------------------------------------------------------------------
// Fused SAGE linear on MFMA: out = [relu]( mean @ Wl + xin @ Wr + b ), bf16 io.
// ---------------------------------------------------------------------------
__global__ __launch_bounds__(256) void sage_linear_mfma_kernel(
        const unsigned short* __restrict__ mean,
        const unsigned short* __restrict__ xin,
        const unsigned short* __restrict__ pwl,
        const unsigned short* __restrict__ pwr,
        const float* __restrict__ bias,
        unsigned short* __restrict__ outp,
        int n_nodes, int do_relu) {
    int lane = threadIdx.x & 63;
    int wid  = threadIdx.x >> 6;
    int arow = lane & 15;
    int kgrp = lane >> 4;

    short8 wl[4][2], wr[4][2];
#pragma unroll
    for (int ct = 0; ct < 4; ++ct)
#pragma unroll
        for (int kk = 0; kk < 2; ++kk) {
            wl[ct][kk] = *(const short8*)(pwl + (((ct * 2 + kk) * 64 + lane) << 3));
            wr[ct][kk] = *(const short8*)(pwr + (((ct * 2 + kk) * 64 + lane) << 3));
        }
    float bj[4];
#pragma unroll
    for (int ct = 0; ct < 4; ++ct) bj[ct] = bias[ct * 16 + arow];

    int wave   = blockIdx.x * 4 + wid;
    int nwaves = gridDim.x * 4;
    int ntiles = (n_nodes + 15) >> 4;

    for (int t = wave; t < ntiles; t += nwaves) {
        int base = t * 16;
        int lrow = base + arow;
        if (lrow >= n_nodes) lrow = n_nodes - 1;
        const unsigned short* mrow = mean + (size_t)lrow * D + kgrp * 8;
        const unsigned short* xrow = xin  + (size_t)lrow * D + kgrp * 8;
        short8 am0 = *(const short8*)(mrow);
        short8 am1 = *(const short8*)(mrow + 32);
        short8 ax0 = *(const short8*)(xrow);
        short8 ax1 = *(const short8*)(xrow + 32);

#pragma unroll
        for (int ct = 0; ct < 4; ++ct) {
            f32x4 acc = {0.f, 0.f, 0.f, 0.f};
            acc = __builtin_amdgcn_mfma_f32_16x16x32_bf16(am0, wl[ct][0], acc, 0, 0, 0);
            acc = __builtin_amdgcn_mfma_f32_16x16x32_bf16(am1, wl[ct][1], acc, 0, 0, 0);
            acc = __builtin_amdgcn_mfma_f32_16x16x32_bf16(ax0, wr[ct][0], acc, 0, 0, 0);
            acc = __builtin_amdgcn_mfma_f32_16x16x32_bf16(ax1, wr[ct][1], acc, 0, 0, 0);
            int col = ct * 16 + arow;
#pragma unroll
            for (int rr = 0; rr < 4; ++rr) {
                int row = base + kgrp * 4 + rr;
                float v = acc[rr] + bj[ct];
                if (do_relu) v = fmaxf(v, 0.0f);
                if (row < n_nodes) outp[(size_t)row * D + col] = f2bf(v);
            }
        }
    }
}

// ---------------------------------------------------------------------------
// Edge decode v2: 16-lane group per edge (4 edges/wave). Lane covers 4 dims
// via dwordx2; 4-step group reduction; lane c==0 writes.
// ---------------------------------------------------------------------------
__global__ __launch_bounds__(256) void decode_bf16_kernel(
        const unsigned short* __restrict__ z,
        const int* __restrict__ esrc,
        const int* __restrict__ edst,
        float* __restrict__ out,
        int n) {
    int lane = threadIdx.x & 63;
    int g    = lane >> 4;        // edge slot in wave
    int c    = lane & 15;        // dim quad
    int wave   = (int)((blockIdx.x * blockDim.x + threadIdx.x) >> 6);
    int nwaves = (int)((gridDim.x * blockDim.x) >> 6);
    int niter  = (n + 3) >> 2;

    for (int it = wave; it < niter; it += nwaves) {
        int e  = it * 4 + g;
        int ec = min(e, n - 1);
        int s  = esrc[ec];
        int d0 = edst[ec];
        ushort4 vs = *(const ushort4*)(z + ((size_t)s  << 6) + (c << 2));
        ushort4 vd = *(const ushort4*)(z + ((size_t)d0 << 6) + (c << 2));
        float p = bf2f(vs.x) * bf2f(vd.x) + bf2f(vs.y) * bf2f(vd.y) +
                  bf2f(vs.z) * bf2f(vd.z) + bf2f(vs.w) * bf2f(vd.w);
        p += __shfl_xor(p, 1);
        p += __shfl_xor(p, 2);
        p += __shfl_xor(p, 4);
        p += __shfl_xor(p, 8);
        if (c == 0 && e < n) out[e] = p;
    }
}

extern "C" void kernel_launch(void* const* d_in, const int* in_sizes, int n_in,
                              void* d_out, int out_size, void* d_ws, size_t ws_size,
                              hipStream_t stream) {
    const float* x   = (const float*)d_in[0];
    const int*   ei  = (const int*)d_in[1];   // [2, E]: src row then dst row
    const int*   eli = (const int*)d_in[2];   // [2, L]
    const float* W1l = (const float*)d_in[3];
    const float* W1r = (const float*)d_in[4];
    const float* b1  = (const float*)d_in[5];
    const float* W2l = (const float*)d_in[6];
    const float* W2r = (const float*)d_in[7];
    const float* b2  = (const float*)d_in[8];
    float* out = (float*)d_out;

    const int n_nodes = in_sizes[0] / D;
    const int n_edges = in_sizes[1] / 2;
    const int n_label = in_sizes[2] / 2;
    const int n_buckets = (n_nodes + NODES_PER_B - 1) >> NB_SHIFT;

    const int* e_src = ei;
    const int* e_dst = ei + n_edges;
    const int* l_src = eli;
    const int* l_dst = eli + n_label;

    // Workspace layout:
    //   xb, meanb, h, z : N*64 ushort each
    //   rowp : N+1 ints; ssrc : E + 8 ints (8 pad for clamped group reads)
    //   gcount, gbase : 256 ints; pw : 4*4096 ushort
    //   binned aliases h..z
    unsigned short* xb    = (unsigned short*)d_ws;
    unsigned short* meanb = xb + (size_t)n_nodes * D;
    unsigned short* h     = meanb + (size_t)n_nodes * D;
    unsigned short* z     = h + (size_t)n_nodes * D;
    int* rowp   = (int*)(z + (size_t)n_nodes * D);
    int* ssrc   = rowp + (n_nodes + 1);
    int* gcount = ssrc + n_edges + 8;
    int* gbase  = gcount + 256;
    unsigned short* pw = (unsigned short*)(gbase + 256);
    unsigned short* pw1l = pw;
    unsigned short* pw1r = pw + 4096;
    unsigned short* pw2l = pw + 8192;
    unsigned short* pw2r = pw + 12288;
    int2* binned = (int2*)h;

    dim3 blk(256);
    dim3 grd_nodes(2048);
    dim3 grd_linear(512);

    // ---- Input convert + weight pack ----
    f32_to_bf16_kernel<<<grd_nodes, blk, 0, stream>>>(x, xb, n_nodes * D / 4);
    pack_w4_kernel<<<dim3(64), blk, 0, stream>>>(W1l, W1r, W2l, W2r, pw);

    // ---- CSR build ----
    hipMemsetAsync(gcount, 0, 256 * sizeof(int), stream);
    bin_edges_kernel<<<dim3(512), blk, 0, stream>>>(e_src, e_dst, gcount, binned,
                                                    n_edges, n_buckets);
    bucket_scan_kernel<<<dim3(1), blk, 0, stream>>>(gcount, gbase, rowp,
                                                    n_buckets, n_nodes, n_edges);
    build_csr_kernel<<<dim3(n_buckets), blk, 0, stream>>>(binned, gcount, gbase,
                                                          rowp, ssrc, n_nodes);

    // ---- Layer 1 ----
    aggregate_bf16_kernel<<<grd_nodes, blk, 0, stream>>>(xb, rowp, ssrc, meanb, n_nodes);
    sage_linear_mfma_kernel<<<grd_linear, blk, 0, stream>>>(meanb, xb, pw1l, pw1r, b1,
                                                            h, n_nodes, /*relu=*/1);

    // ---- Layer 2 ----
    aggregate_bf16_kernel<<<grd_nodes, blk, 0, stream>>>(h, rowp, ssrc, meanb, n_nodes);
    sage_linear_mfma_kernel<<<grd_linear, blk, 0, stream>>>(meanb, h, pw2l, pw2r, b2,
                                                            z, n_nodes, /*relu=*/0);

    // ---- Decode ----
    decode_bf16_kernel<<<grd_nodes, blk, 0, stream>>>(z, l_src, l_dst, out, n_label);
}

// Round 7
// 144.879 us; speedup vs baseline: 5.8273x; 1.0793x over previous
//
#include <hip/hip_runtime.h>

#define D 64
#define NB_SHIFT 9          // 512 nodes per bucket
#define NODES_PER_B 512
#define CAP1 12288          // max edges per bucket (mean ~5120)

typedef __attribute__((ext_vector_type(8))) short short8;
typedef __attribute__((ext_vector_type(4))) float f32x4;

__device__ inline unsigned short f2bf(float f) {
    unsigned int u = __float_as_uint(f);
    return (unsigned short)((u + 0x7FFFu + ((u >> 16) & 1u)) >> 16);  // RNE
}
__device__ inline float bf2f(unsigned short s) {
    return __uint_as_float(((unsigned int)s) << 16);
}

// ---------------------------------------------------------------------------
// fp32 -> bf16 bulk convert
// ---------------------------------------------------------------------------
__global__ void f32_to_bf16_kernel(const float* __restrict__ in,
                                   unsigned short* __restrict__ outp, int n4) {
    int i = blockIdx.x * blockDim.x + threadIdx.x;
    int stride = gridDim.x * blockDim.x;
    for (int t = i; t < n4; t += stride) {
        float4 v = ((const float4*)in)[t];
        ushort4 o;
        o.x = f2bf(v.x); o.y = f2bf(v.y); o.z = f2bf(v.z); o.w = f2bf(v.w);
        ((ushort4*)outp)[t] = o;
    }
}

// ---------------------------------------------------------------------------
// Pass 1: bin edges by dst bucket (dst>>9). Payload packed: (src<<9)|dst_low.
// ---------------------------------------------------------------------------
__global__ __launch_bounds__(256) void bin_edges_kernel(
        const int* __restrict__ src, const int* __restrict__ dst,
        int* __restrict__ gcount, int* __restrict__ binned,
        int n_edges, int n_buckets) {
    __shared__ int lhist[256];
    __shared__ int lbase[256];
    int tid = threadIdx.x;
    int per = (n_edges + gridDim.x - 1) / gridDim.x;
    int beg = blockIdx.x * per;
    int end = min(beg + per, n_edges);

    lhist[tid] = 0;
    __syncthreads();
    for (int e = beg + tid; e < end; e += 256)
        atomicAdd(&lhist[dst[e] >> NB_SHIFT], 1);
    __syncthreads();
    if (tid < n_buckets && lhist[tid] > 0)
        lbase[tid] = atomicAdd(&gcount[tid], lhist[tid]);
    else
        lbase[tid] = 0;
    __syncthreads();
    lhist[tid] = 0;   // reuse as running cursor
    __syncthreads();
    for (int e = beg + tid; e < end; e += 256) {
        int d = dst[e];
        int b = d >> NB_SHIFT;
        int off = lbase[b] + atomicAdd(&lhist[b], 1);
        if (off < CAP1)
            binned[(size_t)b * CAP1 + off] =
                (src[e] << NB_SHIFT) | (d & (NODES_PER_B - 1));
    }
}

// ---------------------------------------------------------------------------
// Pass 2: one block per bucket. Inline scan of the 196-entry bucket-count
// array gives this bucket's base (no separate scan kernel). Then local degree
// histogram -> LDS scan -> coalesced rowp + ssrc.
// ---------------------------------------------------------------------------
__global__ __launch_bounds__(256) void build_csr_kernel(
        const int* __restrict__ binned, const int* __restrict__ gcount,
        int* __restrict__ rowp, int* __restrict__ ssrc,
        int n_nodes, int n_buckets, int n_edges) {
    __shared__ int lhist[NODES_PER_B];
    __shared__ int lbase[NODES_PER_B];
    __shared__ int tmp[256];
    __shared__ int stage[CAP1];

    int b   = blockIdx.x;
    int tid = threadIdx.x;

    // inclusive scan over bucket counts -> this bucket's global base
    int v = (tid < n_buckets) ? min(gcount[tid], CAP1) : 0;
    tmp[tid] = v;
    __syncthreads();
    for (int off = 1; off < 256; off <<= 1) {
        int t = 0;
        if (tid >= off) t = tmp[tid - off];
        __syncthreads();
        if (tid >= off) tmp[tid] += t;
        __syncthreads();
    }
    int base = (b == 0) ? 0 : tmp[b - 1];
    int cnt  = min(gcount[b], CAP1);
    if (b == 0 && tid == 0) rowp[n_nodes] = n_edges;
    __syncthreads();

    int nodebase = b << NB_SHIFT;
    int nlocal   = min(NODES_PER_B, n_nodes - nodebase);
    const int* ebuf = binned + (size_t)b * CAP1;

    lhist[tid] = 0;
    lhist[tid + 256] = 0;
    __syncthreads();
    for (int i = tid; i < cnt; i += 256)
        atomicAdd(&lhist[ebuf[i] & (NODES_PER_B - 1)], 1);
    __syncthreads();

    int a0 = lhist[2 * tid];
    int a1 = lhist[2 * tid + 1];
    tmp[tid] = a0 + a1;
    __syncthreads();
    for (int off = 1; off < 256; off <<= 1) {
        int t = 0;
        if (tid >= off) t = tmp[tid - off];
        __syncthreads();
        if (tid >= off) tmp[tid] += t;
        __syncthreads();
    }
    int excl = tmp[tid] - (a0 + a1);
    lbase[2 * tid]     = excl;
    lbase[2 * tid + 1] = excl + a0;
    __syncthreads();

    for (int j = tid; j < nlocal; j += 256)
        rowp[nodebase + j] = base + lbase[j];

    lhist[tid] = 0;
    lhist[tid + 256] = 0;
    __syncthreads();

    for (int i = tid; i < cnt; i += 256) {
        int e  = ebuf[i];
        int ln = e & (NODES_PER_B - 1);
        int off = atomicAdd(&lhist[ln], 1);
        stage[lbase[ln] + off] = e >> NB_SHIFT;
    }
    __syncthreads();

    for (int i = tid; i < cnt; i += 256)
        ssrc[base + i] = stage[i];
}

// ---------------------------------------------------------------------------
// Pack 4 weight matrices into MFMA B-fragment order, bf16.
// ---------------------------------------------------------------------------
__global__ void pack_w4_kernel(const float* __restrict__ W0,
                               const float* __restrict__ W1,
                               const float* __restrict__ W2,
                               const float* __restrict__ W3,
                               unsigned short* __restrict__ pw) {
    int idx = blockIdx.x * blockDim.x + threadIdx.x;
    if (idx >= 4 * 4096) return;
    int m = idx >> 12;
    int r = idx & 4095;
    const float* W = (m == 0) ? W0 : (m == 1) ? W1 : (m == 2) ? W2 : W3;
    int j    = r & 7;
    int lane = (r >> 3) & 63;
    int kk   = (r >> 9) & 1;
    int ct   = r >> 10;
    int k    = kk * 32 + ((lane >> 4) & 3) * 8 + j;
    int col  = ct * 16 + (lane & 15);
    pw[idx] = f2bf(W[k * D + col]);
}

// ---------------------------------------------------------------------------
// Mean aggregation v3: wave per node, contiguous node chunk per wave
// (sequential rowp/ssrc). Lane = (row-group r = lane>>4, dim-quad c = lane&15).
// 16 edges per iteration via 4 ushort4 gather loads in flight (single
// iteration for deg<=16, ~97% of nodes). Clamped edge ids broadcast to one
// line (cheap). 2-stage butterfly; 16 lanes write the row.
// ---------------------------------------------------------------------------
__global__ __launch_bounds__(256) void aggregate_bf16_kernel(
        const unsigned short* __restrict__ feat,
        const int* __restrict__ row_ptr,
        const int* __restrict__ sorted_src,
        unsigned short* __restrict__ mean_out,
        int n_nodes) {
    int lane = threadIdx.x & 63;
    int r    = lane >> 4;
    int c    = lane & 15;
    int wave   = (int)((blockIdx.x * blockDim.x + threadIdx.x) >> 6);
    int nwaves = (int)((gridDim.x * blockDim.x) >> 6);
    int npw  = (n_nodes + nwaves - 1) / nwaves;
    int nbeg = wave * npw;
    int nend = min(nbeg + npw, n_nodes);
    if (nbeg >= nend) return;

    int beg = row_ptr[nbeg];
    for (int node = nbeg; node < nend; ++node) {
        int end = row_ptr[node + 1];
        int endm1 = end - 1;
        float a0 = 0.f, a1 = 0.f, a2 = 0.f, a3 = 0.f;

        for (int i = beg; i < end; i += 16) {
            int e0 = i + r, e1 = i + 4 + r, e2 = i + 8 + r, e3 = i + 12 + r;
            int s0 = sorted_src[min(e0, endm1)];
            int s1 = sorted_src[min(e1, endm1)];
            int s2 = sorted_src[min(e2, endm1)];
            int s3 = sorted_src[min(e3, endm1)];
            ushort4 v0 = *(const ushort4*)(feat + ((size_t)s0 << 6) + (c << 2));
            ushort4 v1 = *(const ushort4*)(feat + ((size_t)s1 << 6) + (c << 2));
            ushort4 v2 = *(const ushort4*)(feat + ((size_t)s2 << 6) + (c << 2));
            ushort4 v3 = *(const ushort4*)(feat + ((size_t)s3 << 6) + (c << 2));
            if (e0 < end) {
                a0 += bf2f(v0.x); a1 += bf2f(v0.y);
                a2 += bf2f(v0.z); a3 += bf2f(v0.w);
            }
            if (e1 < end) {
                a0 += bf2f(v1.x); a1 += bf2f(v1.y);
                a2 += bf2f(v1.z); a3 += bf2f(v1.w);
            }
            if (e2 < end) {
                a0 += bf2f(v2.x); a1 += bf2f(v2.y);
                a2 += bf2f(v2.z); a3 += bf2f(v2.w);
            }
            if (e3 < end) {
                a0 += bf2f(v3.x); a1 += bf2f(v3.y);
                a2 += bf2f(v3.z); a3 += bf2f(v3.w);
            }
        }
        a0 += __shfl_xor(a0, 16); a1 += __shfl_xor(a1, 16);
        a2 += __shfl_xor(a2, 16); a3 += __shfl_xor(a3, 16);
        a0 += __shfl_xor(a0, 32); a1 += __shfl_xor(a1, 32);
        a2 += __shfl_xor(a2, 32); a3 += __shfl_xor(a3, 32);

        float inv = 1.0f / (float)max(end - beg, 1);
        if (r == 0) {
            ushort4 o;
            o.x = f2bf(a0 * inv); o.y = f2bf(a1 * inv);
            o.z = f2bf(a2 * inv); o.w = f2bf(a3 * inv);
            *(ushort4*)(mean_out + ((size_t)node << 6) + (c << 2)) = o;
        }
        beg = end;
    }
}

// ---------------------------------------------------------------------------
// Fused SAGE linear on MFMA: out = [relu]( mean @ Wl + xin @ Wr + b ), bf16 io.
// ---------------------------------------------------------------------------
__global__ __launch_bounds__(256) void sage_linear_mfma_kernel(
        const unsigned short* __restrict__ mean,
        const unsigned short* __restrict__ xin,
        const unsigned short* __restrict__ pwl,
        const unsigned short* __restrict__ pwr,
        const float* __restrict__ bias,
        unsigned short* __restrict__ outp,
        int n_nodes, int do_relu) {
    int lane = threadIdx.x & 63;
    int wid  = threadIdx.x >> 6;
    int arow = lane & 15;
    int kgrp = lane >> 4;

    short8 wl[4][2], wr[4][2];
#pragma unroll
    for (int ct = 0; ct < 4; ++ct)
#pragma unroll
        for (int kk = 0; kk < 2; ++kk) {
            wl[ct][kk] = *(const short8*)(pwl + (((ct * 2 + kk) * 64 + lane) << 3));
            wr[ct][kk] = *(const short8*)(pwr + (((ct * 2 + kk) * 64 + lane) << 3));
        }
    float bj[4];
#pragma unroll
    for (int ct = 0; ct < 4; ++ct) bj[ct] = bias[ct * 16 + arow];

    int wave   = blockIdx.x * 4 + wid;
    int nwaves = gridDim.x * 4;
    int ntiles = (n_nodes + 15) >> 4;

    for (int t = wave; t < ntiles; t += nwaves) {
        int base = t * 16;
        int lrow = base + arow;
        if (lrow >= n_nodes) lrow = n_nodes - 1;
        const unsigned short* mrow = mean + (size_t)lrow * D + kgrp * 8;
        const unsigned short* xrow = xin  + (size_t)lrow * D + kgrp * 8;
        short8 am0 = *(const short8*)(mrow);
        short8 am1 = *(const short8*)(mrow + 32);
        short8 ax0 = *(const short8*)(xrow);
        short8 ax1 = *(const short8*)(xrow + 32);

#pragma unroll
        for (int ct = 0; ct < 4; ++ct) {
            f32x4 acc = {0.f, 0.f, 0.f, 0.f};
            acc = __builtin_amdgcn_mfma_f32_16x16x32_bf16(am0, wl[ct][0], acc, 0, 0, 0);
            acc = __builtin_amdgcn_mfma_f32_16x16x32_bf16(am1, wl[ct][1], acc, 0, 0, 0);
            acc = __builtin_amdgcn_mfma_f32_16x16x32_bf16(ax0, wr[ct][0], acc, 0, 0, 0);
            acc = __builtin_amdgcn_mfma_f32_16x16x32_bf16(ax1, wr[ct][1], acc, 0, 0, 0);
            int col = ct * 16 + arow;
#pragma unroll
            for (int rr = 0; rr < 4; ++rr) {
                int row = base + kgrp * 4 + rr;
                float v = acc[rr] + bj[ct];
                if (do_relu) v = fmaxf(v, 0.0f);
                if (row < n_nodes) outp[(size_t)row * D + col] = f2bf(v);
            }
        }
    }
}

// ---------------------------------------------------------------------------
// Edge decode: 16-lane group per edge (4 edges/wave), ushort4 loads,
// 4-step group reduction.
// ---------------------------------------------------------------------------
__global__ __launch_bounds__(256) void decode_bf16_kernel(
        const unsigned short* __restrict__ z,
        const int* __restrict__ esrc,
        const int* __restrict__ edst,
        float* __restrict__ out,
        int n) {
    int lane = threadIdx.x & 63;
    int g    = lane >> 4;
    int c    = lane & 15;
    int wave   = (int)((blockIdx.x * blockDim.x + threadIdx.x) >> 6);
    int nwaves = (int)((gridDim.x * blockDim.x) >> 6);
    int niter  = (n + 3) >> 2;

    for (int it = wave; it < niter; it += nwaves) {
        int e  = it * 4 + g;
        int ec = min(e, n - 1);
        int s  = esrc[ec];
        int d0 = edst[ec];
        ushort4 vs = *(const ushort4*)(z + ((size_t)s  << 6) + (c << 2));
        ushort4 vd = *(const ushort4*)(z + ((size_t)d0 << 6) + (c << 2));
        float p = bf2f(vs.x) * bf2f(vd.x) + bf2f(vs.y) * bf2f(vd.y) +
                  bf2f(vs.z) * bf2f(vd.z) + bf2f(vs.w) * bf2f(vd.w);
        p += __shfl_xor(p, 1);
        p += __shfl_xor(p, 2);
        p += __shfl_xor(p, 4);
        p += __shfl_xor(p, 8);
        if (c == 0 && e < n) out[e] = p;
    }
}

extern "C" void kernel_launch(void* const* d_in, const int* in_sizes, int n_in,
                              void* d_out, int out_size, void* d_ws, size_t ws_size,
                              hipStream_t stream) {
    const float* x   = (const float*)d_in[0];
    const int*   ei  = (const int*)d_in[1];   // [2, E]: src row then dst row
    const int*   eli = (const int*)d_in[2];   // [2, L]
    const float* W1l = (const float*)d_in[3];
    const float* W1r = (const float*)d_in[4];
    const float* b1  = (const float*)d_in[5];
    const float* W2l = (const float*)d_in[6];
    const float* W2r = (const float*)d_in[7];
    const float* b2  = (const float*)d_in[8];
    float* out = (float*)d_out;

    const int n_nodes = in_sizes[0] / D;
    const int n_edges = in_sizes[1] / 2;
    const int n_label = in_sizes[2] / 2;
    const int n_buckets = (n_nodes + NODES_PER_B - 1) >> NB_SHIFT;

    const int* e_src = ei;
    const int* e_dst = ei + n_edges;
    const int* l_src = eli;
    const int* l_dst = eli + n_label;

    // Workspace layout:
    //   xb, meanb, h, z : N*64 ushort each
    //   rowp : N+1 ints; ssrc : E + 8 ints
    //   gcount : 256 ints; pw : 4*4096 ushort
    //   binned (packed ints, ~9.6 MB) aliases h..z
    unsigned short* xb    = (unsigned short*)d_ws;
    unsigned short* meanb = xb + (size_t)n_nodes * D;
    unsigned short* h     = meanb + (size_t)n_nodes * D;
    unsigned short* z     = h + (size_t)n_nodes * D;
    int* rowp   = (int*)(z + (size_t)n_nodes * D);
    int* ssrc   = rowp + (n_nodes + 1);
    int* gcount = ssrc + n_edges + 8;
    unsigned short* pw = (unsigned short*)(gcount + 256);
    unsigned short* pw1l = pw;
    unsigned short* pw1r = pw + 4096;
    unsigned short* pw2l = pw + 8192;
    unsigned short* pw2r = pw + 12288;
    int* binned = (int*)h;

    dim3 blk(256);
    dim3 grd_nodes(2048);
    dim3 grd_linear(512);

    // ---- Input convert + weight pack ----
    f32_to_bf16_kernel<<<grd_nodes, blk, 0, stream>>>(x, xb, n_nodes * D / 4);
    pack_w4_kernel<<<dim3(64), blk, 0, stream>>>(W1l, W1r, W2l, W2r, pw);

    // ---- CSR build ----
    hipMemsetAsync(gcount, 0, 256 * sizeof(int), stream);
    bin_edges_kernel<<<dim3(512), blk, 0, stream>>>(e_src, e_dst, gcount, binned,
                                                    n_edges, n_buckets);
    build_csr_kernel<<<dim3(n_buckets), blk, 0, stream>>>(binned, gcount, rowp,
                                                          ssrc, n_nodes,
                                                          n_buckets, n_edges);

    // ---- Layer 1 ----
    aggregate_bf16_kernel<<<grd_nodes, blk, 0, stream>>>(xb, rowp, ssrc, meanb, n_nodes);
    sage_linear_mfma_kernel<<<grd_linear, blk, 0, stream>>>(meanb, xb, pw1l, pw1r, b1,
                                                            h, n_nodes, /*relu=*/1);

    // ---- Layer 2 ----
    aggregate_bf16_kernel<<<grd_nodes, blk, 0, stream>>>(h, rowp, ssrc, meanb, n_nodes);
    sage_linear_mfma_kernel<<<grd_linear, blk, 0, stream>>>(meanb, h, pw2l, pw2r, b2,
                                                            z, n_nodes, /*relu=*/0);

    // ---- Decode ----
    decode_bf16_kernel<<<grd_nodes, blk, 0, stream>>>(z, l_src, l_dst, out, n_label);
}